// Round 1
// baseline (361.813 us; speedup 1.0000x reference)
//
#include <hip/hip_runtime.h>
#include <stdint.h>

typedef __bf16 v8bf __attribute__((ext_vector_type(8)));
typedef float  v4f  __attribute__((ext_vector_type(4)));
typedef unsigned short u16;

static constexpr int B_ = 4, S_ = 4096, D_ = 256, E_ = 512;
// scale (1/sqrt(256)) folded with log2(e) for native v_exp_f32 (2^x)
static constexpr float SC_ = 0.09016844005555897f; // (1/16) * log2(e)

__device__ __forceinline__ v8bf ldfrag(const u16* p) {
    return __builtin_bit_cast(v8bf, *(const uint4*)p);
}
__device__ __forceinline__ u16 f2bf(float f) {
    return __builtin_bit_cast(u16, (__bf16)f);
}

// ---------------- W fp32 -> bf16 ----------------
__global__ void k_convw(const float* __restrict__ Wf, u16* __restrict__ Wb) {
    int i = blockIdx.x * 256 + threadIdx.x;           // grid 512 -> 131072
    Wb[i] = f2bf(Wf[i]);
}

// ---------------- projection: QK = x @ W^T + b, split-store bf16 Q,K -------
__global__ __launch_bounds__(256) void k_proj(const float* __restrict__ x,
                                              const u16* __restrict__ Wb,
                                              const float* __restrict__ bias,
                                              u16* __restrict__ Qb,
                                              u16* __restrict__ Kb) {
    const int tid = threadIdx.x, wave = tid >> 6, lane = tid & 63;
    const int l15 = lane & 15, quad = lane >> 4;
    const int nchunk = blockIdx.x & 3;                 // 4 chunks of 128 units
    const int tt = ((blockIdx.x >> 2) << 2) + wave;    // token tile 0..1023
    const int tbase = tt * 16;

    // preload A fragments: x rows -> bf16
    v8bf a[8];
    const float* xrow = x + (size_t)(tbase + l15) * D_ + quad * 8;
#pragma unroll
    for (int j = 0; j < 8; ++j) {
        float4 f0 = *(const float4*)(xrow + j * 32);
        float4 f1 = *(const float4*)(xrow + j * 32 + 4);
        v8bf t;
        t[0] = (__bf16)f0.x; t[1] = (__bf16)f0.y; t[2] = (__bf16)f0.z; t[3] = (__bf16)f0.w;
        t[4] = (__bf16)f1.x; t[5] = (__bf16)f1.y; t[6] = (__bf16)f1.z; t[7] = (__bf16)f1.w;
        a[j] = t;
    }

    for (int nt = 0; nt < 8; ++nt) {
        const int nb = nchunk * 128 + nt * 16;
        const u16* wrow = Wb + (nb + l15) * D_ + quad * 8;
        v4f acc = {0.f, 0.f, 0.f, 0.f};
#pragma unroll
        for (int j = 0; j < 8; ++j) {
            v8bf bf = ldfrag(wrow + j * 32);
            acc = __builtin_amdgcn_mfma_f32_16x16x32_bf16(a[j], bf, acc, 0, 0, 0);
        }
        const float bv = bias[nb + l15];
        const int unit = nb + l15;
#pragma unroll
        for (int r = 0; r < 4; ++r) {
            const int tok = tbase + quad * 4 + r;
            const u16 v = f2bf(acc[r] + bv);
            if (unit < D_) Qb[tok * D_ + unit] = v;
            else           Kb[tok * D_ + (unit - D_)] = v;
        }
    }
}

// ---------------- pass A: Z_q = sum_k exp(l*scale) (no max needed) ---------
__global__ __launch_bounds__(256) void k_passA(const u16* __restrict__ Qb,
                                               const u16* __restrict__ Kb,
                                               float* __restrict__ Z) {
    const int tid = threadIdx.x, wave = tid >> 6, lane = tid & 63;
    const int l15 = lane & 15, quad = lane >> 4;
    const int blk = blockIdx.x;                 // 1024
    const int b = blk >> 8;
    const int rem = blk & 255;
    const int ks = rem & 7;                     // key split: 8 x 512 keys
    const int qg = ((rem >> 3) << 2) + wave;    // 0..127  (32 queries each)
    const int qbase = qg * 32;
    const int kstart = ks * 512;

    const u16* qrow0 = Qb + (b * S_ + qbase + l15) * D_ + quad * 8;
    const u16* qrow1 = qrow0 + 16 * D_;
    v8bf a0[8], a1[8];
#pragma unroll
    for (int j = 0; j < 8; ++j) { a0[j] = ldfrag(qrow0 + j * 32); a1[j] = ldfrag(qrow1 + j * 32); }

    float z0[4] = {0, 0, 0, 0}, z1[4] = {0, 0, 0, 0};
    const u16* krow = Kb + (b * S_ + kstart + l15) * D_ + quad * 8;

    for (int t = 0; t < 32; ++t) {              // 32 tiles x 16 keys = 512
        v4f acc0 = {0.f, 0.f, 0.f, 0.f}, acc1 = {0.f, 0.f, 0.f, 0.f};
#pragma unroll
        for (int j = 0; j < 8; ++j) {
            v8bf bf = ldfrag(krow + j * 32);
            acc0 = __builtin_amdgcn_mfma_f32_16x16x32_bf16(a0[j], bf, acc0, 0, 0, 0);
            acc1 = __builtin_amdgcn_mfma_f32_16x16x32_bf16(a1[j], bf, acc1, 0, 0, 0);
        }
#pragma unroll
        for (int r = 0; r < 4; ++r) {
            z0[r] += __builtin_amdgcn_exp2f(acc0[r] * SC_);
            z1[r] += __builtin_amdgcn_exp2f(acc1[r] * SC_);
        }
        krow += 16 * D_;
        if ((t & 7) == 7) __syncthreads();      // keep block's waves on same K stream (L1 reuse)
    }

#pragma unroll
    for (int r = 0; r < 4; ++r) {
#pragma unroll
        for (int off = 1; off < 16; off <<= 1) {
            z0[r] += __shfl_xor(z0[r], off);
            z1[r] += __shfl_xor(z1[r], off);
        }
    }
    if (l15 == 0) {
#pragma unroll
        for (int r = 0; r < 4; ++r) {
            atomicAdd(&Z[b * S_ + qbase + quad * 4 + r], z0[r]);
            atomicAdd(&Z[b * S_ + qbase + 16 + quad * 4 + r], z1[r]);
        }
    }
}

// ---------------- reciprocal of Z ----------------
__global__ void k_rcp(const float* __restrict__ Z, float* __restrict__ rZ) {
    int i = blockIdx.x * 256 + threadIdx.x;    // grid 64 -> 16384
    rZ[i] = 1.0f / Z[i];
}

// ---------------- pass B: w_k = sum_q exp(l*scale) / Z_q -------------------
__global__ __launch_bounds__(256) void k_passB(const u16* __restrict__ Qb,
                                               const u16* __restrict__ Kb,
                                               const float* __restrict__ rZ,
                                               float* __restrict__ w) {
    const int tid = threadIdx.x, wave = tid >> 6, lane = tid & 63;
    const int l15 = lane & 15, quad = lane >> 4;
    const int blk = blockIdx.x;                 // 1024
    const int b = blk >> 8;
    const int rem = blk & 255;
    const int qs = rem & 7;                     // query split: 8 x 512 queries
    const int kg = ((rem >> 3) << 2) + wave;    // 0..127 (32 keys each)
    const int kbase = kg * 32;
    const int qstart = qs * 512;

    const u16* krow0 = Kb + (b * S_ + kbase + l15) * D_ + quad * 8;
    const u16* krow1 = krow0 + 16 * D_;
    v8bf b0[8], b1[8];
#pragma unroll
    for (int j = 0; j < 8; ++j) { b0[j] = ldfrag(krow0 + j * 32); b1[j] = ldfrag(krow1 + j * 32); }

    float w0 = 0.f, w1 = 0.f;
    const u16* qrow = Qb + (b * S_ + qstart + l15) * D_ + quad * 8;
    const float* rzp = rZ + b * S_ + qstart + quad * 4;

    for (int t = 0; t < 32; ++t) {
        v4f acc0 = {0.f, 0.f, 0.f, 0.f}, acc1 = {0.f, 0.f, 0.f, 0.f};
#pragma unroll
        for (int j = 0; j < 8; ++j) {
            v8bf af = ldfrag(qrow + j * 32);
            acc0 = __builtin_amdgcn_mfma_f32_16x16x32_bf16(af, b0[j], acc0, 0, 0, 0);
            acc1 = __builtin_amdgcn_mfma_f32_16x16x32_bf16(af, b1[j], acc1, 0, 0, 0);
        }
#pragma unroll
        for (int r = 0; r < 4; ++r) {
            const float rz = rzp[r];
            w0 += __builtin_amdgcn_exp2f(acc0[r] * SC_) * rz;
            w1 += __builtin_amdgcn_exp2f(acc1[r] * SC_) * rz;
        }
        qrow += 16 * D_;
        rzp += 16;
        if ((t & 7) == 7) __syncthreads();
    }

    // sum over the 4 query-row groups (quads): lanes with same l15
    w0 += __shfl_xor(w0, 16); w0 += __shfl_xor(w0, 32);
    w1 += __shfl_xor(w1, 16); w1 += __shfl_xor(w1, 32);
    if (quad == 0) {
        atomicAdd(&w[b * S_ + kbase + l15], w0);
        atomicAdd(&w[b * S_ + kbase + 16 + l15], w1);
    }
}

// ---------------- final: out[b,d] = sum_k w[b,k] * x[b,k,d] ----------------
__global__ __launch_bounds__(256) void k_final(const float* __restrict__ x,
                                               const float* __restrict__ w,
                                               float* __restrict__ out) {
    const int b = blockIdx.x >> 7, kc = blockIdx.x & 127;  // grid 512
    const int d = threadIdx.x;
    const int k0 = kc * 32;
    float acc = 0.f;
    const float* xp = x + (size_t)(b * S_ + k0) * D_ + d;
    const float* wp = w + b * S_ + k0;
#pragma unroll 8
    for (int kk = 0; kk < 32; ++kk) acc += wp[kk] * xp[(size_t)kk * D_];
    atomicAdd(&out[b * D_ + d], acc);
}

extern "C" void kernel_launch(void* const* d_in, const int* in_sizes, int n_in,
                              void* d_out, int out_size, void* d_ws, size_t ws_size,
                              hipStream_t stream) {
    const float* x    = (const float*)d_in[0];   // [4,4096,256]
    const float* W    = (const float*)d_in[1];   // [512,256]
    const float* bias = (const float*)d_in[2];   // [512]
    float* out = (float*)d_out;                  // [4,256]

    char* ws = (char*)d_ws;
    u16*   Qb = (u16*)ws;                                 //  8 MiB
    u16*   Kb = Qb + (size_t)B_ * S_ * D_;                //  8 MiB
    float* Z  = (float*)(ws + 16777216);                  // 64 KiB
    float* rZ = Z + B_ * S_;                              // 64 KiB
    float* w  = rZ + B_ * S_;                             // 64 KiB
    u16*   Wb = (u16*)(w + B_ * S_);                      // 256 KiB

    hipMemsetAsync(Z, 0, 3 * B_ * S_ * sizeof(float), stream);  // Z, rZ, w
    hipMemsetAsync(out, 0, B_ * D_ * sizeof(float), stream);

    k_convw<<<E_ * D_ / 256, 256, 0, stream>>>(W, Wb);
    k_proj <<<1024, 256, 0, stream>>>(x, Wb, bias, Qb, Kb);
    k_passA<<<1024, 256, 0, stream>>>(Qb, Kb, Z);
    k_rcp  <<<B_ * S_ / 256, 256, 0, stream>>>(Z, rZ);
    k_passB<<<1024, 256, 0, stream>>>(Qb, Kb, rZ, w);
    k_final<<<512, 256, 0, stream>>>(x, w, out);
}

// Round 2
// 252.704 us; speedup vs baseline: 1.4318x; 1.4318x over previous
//
#include <hip/hip_runtime.h>
#include <stdint.h>

typedef __bf16 v8bf __attribute__((ext_vector_type(8)));
typedef float  v4f  __attribute__((ext_vector_type(4)));
typedef unsigned short u16;

static constexpr int B_ = 4, S_ = 4096, D_ = 256, E_ = 512;
// scale (1/sqrt(256)) folded with log2(e); pre-applied to Q in k_proj
static constexpr float SC_ = 0.09016844005555897f; // (1/16) * log2(e)

__device__ __forceinline__ v8bf ldfrag(const u16* p) {
    return __builtin_bit_cast(v8bf, *(const uint4*)p);
}
__device__ __forceinline__ u16 f2bf(float f) {
    return __builtin_bit_cast(u16, (__bf16)f);
}

// ---------------- W fp32 -> bf16 ----------------
__global__ void k_convw(const float* __restrict__ Wf, u16* __restrict__ Wb) {
    int i = blockIdx.x * 256 + threadIdx.x;           // grid 512 -> 131072
    Wb[i] = f2bf(Wf[i]);
}

// ---------------- projection: QK = x @ W^T + b, Q pre-scaled by SC_ --------
__global__ __launch_bounds__(256) void k_proj(const float* __restrict__ x,
                                              const u16* __restrict__ Wb,
                                              const float* __restrict__ bias,
                                              u16* __restrict__ Qb,
                                              u16* __restrict__ Kb) {
    const int tid = threadIdx.x, wave = tid >> 6, lane = tid & 63;
    const int l15 = lane & 15, quad = lane >> 4;
    const int nchunk = blockIdx.x & 3;                 // 4 chunks of 128 units
    const int tt = ((blockIdx.x >> 2) << 2) + wave;    // token tile 0..1023
    const int tbase = tt * 16;

    // preload A fragments: x rows -> bf16
    v8bf a[8];
    const float* xrow = x + (size_t)(tbase + l15) * D_ + quad * 8;
#pragma unroll
    for (int j = 0; j < 8; ++j) {
        float4 f0 = *(const float4*)(xrow + j * 32);
        float4 f1 = *(const float4*)(xrow + j * 32 + 4);
        v8bf t;
        t[0] = (__bf16)f0.x; t[1] = (__bf16)f0.y; t[2] = (__bf16)f0.z; t[3] = (__bf16)f0.w;
        t[4] = (__bf16)f1.x; t[5] = (__bf16)f1.y; t[6] = (__bf16)f1.z; t[7] = (__bf16)f1.w;
        a[j] = t;
    }

    const u16* wbase = Wb + (nchunk * 128 + l15) * D_ + quad * 8;
    v8bf wcur[8], wnxt[8];
#pragma unroll
    for (int j = 0; j < 8; ++j) wcur[j] = ldfrag(wbase + j * 32);

    auto tile = [&](const v8bf (&wb)[8], int nt) {
        const int nb = nchunk * 128 + nt * 16;
        v4f acc = {0.f, 0.f, 0.f, 0.f};
#pragma unroll
        for (int j = 0; j < 8; ++j)
            acc = __builtin_amdgcn_mfma_f32_16x16x32_bf16(a[j], wb[j], acc, 0, 0, 0);
        const float bv = bias[nb + l15];
        const int unit = nb + l15;
#pragma unroll
        for (int r = 0; r < 4; ++r) {
            const int tok = tbase + quad * 4 + r;
            const float val = acc[r] + bv;
            if (unit < D_) Qb[tok * D_ + unit] = f2bf(val * SC_);
            else           Kb[tok * D_ + (unit - D_)] = f2bf(val);
        }
    };

    for (int nt = 0; nt < 8; nt += 2) {
        const u16* wp1 = wbase + (nt + 1) * 16 * D_;
#pragma unroll
        for (int j = 0; j < 8; ++j) wnxt[j] = ldfrag(wp1 + j * 32);
        tile(wcur, nt);
        if (nt + 2 < 8) {
            const u16* wp2 = wbase + (nt + 2) * 16 * D_;
#pragma unroll
            for (int j = 0; j < 8; ++j) wcur[j] = ldfrag(wp2 + j * 32);
        }
        tile(wnxt, nt + 1);
    }
}

// ---------------- pass A: Z_q = sum_k exp2(l_scaled) -----------------------
// 64 stationary q-rows per wave, streamed K tiles double-buffered.
__global__ __launch_bounds__(256, 2) void k_passA(const u16* __restrict__ Qb,
                                                  const u16* __restrict__ Kb,
                                                  float* __restrict__ Z) {
    const int tid = threadIdx.x, wave = tid >> 6, lane = tid & 63;
    const int l15 = lane & 15, quad = lane >> 4;
    const int blk = blockIdx.x;                 // 512
    const int b = blk >> 7;
    const int qg4 = (blk >> 3) & 15;
    const int ks = blk & 7;
    const int qbase = (qg4 * 4 + wave) * 64;    // 64 queries per wave
    const int kstart = ks * 512;

    // stationary: 4 fragment sets of 16 q rows
    v8bf a[4][8];
    const u16* qp = Qb + (size_t)(b * S_ + qbase + l15) * D_ + quad * 8;
#pragma unroll
    for (int s = 0; s < 4; ++s)
#pragma unroll
        for (int j = 0; j < 8; ++j) a[s][j] = ldfrag(qp + s * 16 * D_ + j * 32);

    float z[4][4] = {{0,0,0,0},{0,0,0,0},{0,0,0,0},{0,0,0,0}};

    const u16* kp = Kb + (size_t)(b * S_ + kstart + l15) * D_ + quad * 8;
    v8bf cur[8], nxt[8];
#pragma unroll
    for (int j = 0; j < 8; ++j) cur[j] = ldfrag(kp + j * 32);

    auto compute = [&](const v8bf (&buf)[8]) {
        v4f a0 = {0,0,0,0}, a1 = {0,0,0,0}, a2 = {0,0,0,0}, a3 = {0,0,0,0};
#pragma unroll
        for (int j = 0; j < 8; ++j) {
            a0 = __builtin_amdgcn_mfma_f32_16x16x32_bf16(a[0][j], buf[j], a0, 0, 0, 0);
            a1 = __builtin_amdgcn_mfma_f32_16x16x32_bf16(a[1][j], buf[j], a1, 0, 0, 0);
            a2 = __builtin_amdgcn_mfma_f32_16x16x32_bf16(a[2][j], buf[j], a2, 0, 0, 0);
            a3 = __builtin_amdgcn_mfma_f32_16x16x32_bf16(a[3][j], buf[j], a3, 0, 0, 0);
        }
#pragma unroll
        for (int r = 0; r < 4; ++r) {
            z[0][r] += __builtin_amdgcn_exp2f(a0[r]);
            z[1][r] += __builtin_amdgcn_exp2f(a1[r]);
            z[2][r] += __builtin_amdgcn_exp2f(a2[r]);
            z[3][r] += __builtin_amdgcn_exp2f(a3[r]);
        }
    };

    for (int t = 0; t < 32; t += 2) {
        const u16* kp1 = kp + 16 * D_;
#pragma unroll
        for (int j = 0; j < 8; ++j) nxt[j] = ldfrag(kp1 + j * 32);
        compute(cur);
        if (t + 2 < 32) {
            const u16* kp2 = kp + 32 * D_;
#pragma unroll
            for (int j = 0; j < 8; ++j) cur[j] = ldfrag(kp2 + j * 32);
        }
        compute(nxt);
        kp += 32 * D_;
    }

    // reduce over the 16 keys held across l15 lanes
#pragma unroll
    for (int s = 0; s < 4; ++s)
#pragma unroll
        for (int r = 0; r < 4; ++r) {
#pragma unroll
            for (int off = 1; off < 16; off <<= 1) z[s][r] += __shfl_xor(z[s][r], off);
            if (l15 == 0)
                atomicAdd(&Z[b * S_ + qbase + s * 16 + quad * 4 + r], z[s][r]);
        }
}

// ---------------- reciprocal of Z ----------------
__global__ void k_rcp(const float* __restrict__ Z, float* __restrict__ rZ) {
    int i = blockIdx.x * 256 + threadIdx.x;    // grid 64 -> 16384
    rZ[i] = 1.0f / Z[i];
}

// ---------------- pass B: w_k = sum_q exp2(l_scaled) * rZ_q ----------------
// 64 stationary k-rows per wave, streamed Q tiles + rZ double-buffered.
__global__ __launch_bounds__(256, 2) void k_passB(const u16* __restrict__ Qb,
                                                  const u16* __restrict__ Kb,
                                                  const float* __restrict__ rZ,
                                                  float* __restrict__ w) {
    const int tid = threadIdx.x, wave = tid >> 6, lane = tid & 63;
    const int l15 = lane & 15, quad = lane >> 4;
    const int blk = blockIdx.x;                 // 512
    const int b = blk >> 7;
    const int kg4 = (blk >> 3) & 15;
    const int qs = blk & 7;
    const int kbase = (kg4 * 4 + wave) * 64;    // 64 keys per wave
    const int qstart = qs * 512;

    // stationary: 4 fragment sets of 16 k rows (B operand: n = l15 = key)
    v8bf bk[4][8];
    const u16* kp = Kb + (size_t)(b * S_ + kbase + l15) * D_ + quad * 8;
#pragma unroll
    for (int s = 0; s < 4; ++s)
#pragma unroll
        for (int j = 0; j < 8; ++j) bk[s][j] = ldfrag(kp + s * 16 * D_ + j * 32);

    float wsum[4] = {0, 0, 0, 0};

    const u16* qp = Qb + (size_t)(b * S_ + qstart + l15) * D_ + quad * 8;
    const float* zp = rZ + b * S_ + qstart + quad * 4;
    v8bf cur[8], nxt[8];
    float4 zcur, znxt;
#pragma unroll
    for (int j = 0; j < 8; ++j) cur[j] = ldfrag(qp + j * 32);
    zcur = *(const float4*)zp;

    auto compute = [&](const v8bf (&buf)[8], const float4& rzv) {
        v4f a0 = {0,0,0,0}, a1 = {0,0,0,0}, a2 = {0,0,0,0}, a3 = {0,0,0,0};
#pragma unroll
        for (int j = 0; j < 8; ++j) {
            a0 = __builtin_amdgcn_mfma_f32_16x16x32_bf16(buf[j], bk[0][j], a0, 0, 0, 0);
            a1 = __builtin_amdgcn_mfma_f32_16x16x32_bf16(buf[j], bk[1][j], a1, 0, 0, 0);
            a2 = __builtin_amdgcn_mfma_f32_16x16x32_bf16(buf[j], bk[2][j], a2, 0, 0, 0);
            a3 = __builtin_amdgcn_mfma_f32_16x16x32_bf16(buf[j], bk[3][j], a3, 0, 0, 0);
        }
        wsum[0] += __builtin_amdgcn_exp2f(a0[0]) * rzv.x + __builtin_amdgcn_exp2f(a0[1]) * rzv.y
                 + __builtin_amdgcn_exp2f(a0[2]) * rzv.z + __builtin_amdgcn_exp2f(a0[3]) * rzv.w;
        wsum[1] += __builtin_amdgcn_exp2f(a1[0]) * rzv.x + __builtin_amdgcn_exp2f(a1[1]) * rzv.y
                 + __builtin_amdgcn_exp2f(a1[2]) * rzv.z + __builtin_amdgcn_exp2f(a1[3]) * rzv.w;
        wsum[2] += __builtin_amdgcn_exp2f(a2[0]) * rzv.x + __builtin_amdgcn_exp2f(a2[1]) * rzv.y
                 + __builtin_amdgcn_exp2f(a2[2]) * rzv.z + __builtin_amdgcn_exp2f(a2[3]) * rzv.w;
        wsum[3] += __builtin_amdgcn_exp2f(a3[0]) * rzv.x + __builtin_amdgcn_exp2f(a3[1]) * rzv.y
                 + __builtin_amdgcn_exp2f(a3[2]) * rzv.z + __builtin_amdgcn_exp2f(a3[3]) * rzv.w;
    };

    for (int t = 0; t < 32; t += 2) {
        const u16* qp1 = qp + 16 * D_;
#pragma unroll
        for (int j = 0; j < 8; ++j) nxt[j] = ldfrag(qp1 + j * 32);
        znxt = *(const float4*)(zp + 16);
        compute(cur, zcur);
        if (t + 2 < 32) {
            const u16* qp2 = qp + 32 * D_;
#pragma unroll
            for (int j = 0; j < 8; ++j) cur[j] = ldfrag(qp2 + j * 32);
            zcur = *(const float4*)(zp + 32);
        }
        compute(nxt, znxt);
        qp += 32 * D_;
        zp += 32;
    }

    // reduce over the 4 query quads; lanes quad==0 hold distinct keys
#pragma unroll
    for (int s = 0; s < 4; ++s) {
        wsum[s] += __shfl_xor(wsum[s], 16);
        wsum[s] += __shfl_xor(wsum[s], 32);
        if (quad == 0) atomicAdd(&w[b * S_ + kbase + s * 16 + l15], wsum[s]);
    }
}

// ---------------- final: out[b,d] = sum_k w[b,k] * x[b,k,d] ----------------
__global__ __launch_bounds__(256) void k_final(const float* __restrict__ x,
                                               const float* __restrict__ w,
                                               float* __restrict__ out) {
    const int b = blockIdx.x >> 7, kc = blockIdx.x & 127;  // grid 512
    const int d = threadIdx.x;
    const int k0 = kc * 32;
    float acc = 0.f;
    const float* xp = x + (size_t)(b * S_ + k0) * D_ + d;
    const float* wp = w + b * S_ + k0;
#pragma unroll 8
    for (int kk = 0; kk < 32; ++kk) acc += wp[kk] * xp[(size_t)kk * D_];
    atomicAdd(&out[b * D_ + d], acc);
}

extern "C" void kernel_launch(void* const* d_in, const int* in_sizes, int n_in,
                              void* d_out, int out_size, void* d_ws, size_t ws_size,
                              hipStream_t stream) {
    const float* x    = (const float*)d_in[0];   // [4,4096,256]
    const float* W    = (const float*)d_in[1];   // [512,256]
    const float* bias = (const float*)d_in[2];   // [512]
    float* out = (float*)d_out;                  // [4,256]

    char* ws = (char*)d_ws;
    u16*   Qb = (u16*)ws;                                 //  8 MiB
    u16*   Kb = Qb + (size_t)B_ * S_ * D_;                //  8 MiB
    float* Z  = (float*)(ws + 16777216);                  // 64 KiB
    float* rZ = Z + B_ * S_;                              // 64 KiB
    float* w  = rZ + B_ * S_;                             // 64 KiB
    u16*   Wb = (u16*)(w + B_ * S_);                      // 256 KiB

    hipMemsetAsync(Z, 0, 3 * B_ * S_ * sizeof(float), stream);  // Z, rZ, w
    hipMemsetAsync(out, 0, B_ * D_ * sizeof(float), stream);

    k_convw<<<E_ * D_ / 256, 256, 0, stream>>>(W, Wb);
    k_proj <<<1024, 256, 0, stream>>>(x, Wb, bias, Qb, Kb);
    k_passA<<<512, 256, 0, stream>>>(Qb, Kb, Z);
    k_rcp  <<<B_ * S_ / 256, 256, 0, stream>>>(Z, rZ);
    k_passB<<<512, 256, 0, stream>>>(Qb, Kb, rZ, w);
    k_final<<<512, 256, 0, stream>>>(x, w, out);
}

// Round 3
// 226.154 us; speedup vs baseline: 1.5998x; 1.1174x over previous
//
#include <hip/hip_runtime.h>
#include <stdint.h>

typedef __bf16 v8bf __attribute__((ext_vector_type(8)));
typedef float  v4f  __attribute__((ext_vector_type(4)));
typedef unsigned short u16;

static constexpr int B_ = 4, S_ = 4096, D_ = 256, E_ = 512;
// scale (1/sqrt(256)) folded with log2(e); pre-applied to Q in k_proj
static constexpr float SC_ = 0.09016844005555897f;

#define AS1C(p) ((const __attribute__((address_space(1))) void*)(p))
#define AS3(p)  ((__attribute__((address_space(3))) void*)(p))

__device__ __forceinline__ v8bf ldfrag(const u16* p) {
    return __builtin_bit_cast(v8bf, *(const uint4*)p);
}
__device__ __forceinline__ u16 f2bf(float f) {
    return __builtin_bit_cast(u16, (__bf16)f);
}

// ---------------- W fp32 -> bf16 ----------------
__global__ void k_convw(const float* __restrict__ Wf, u16* __restrict__ Wb) {
    int i = blockIdx.x * 256 + threadIdx.x;           // grid 512 -> 131072
    Wb[i] = f2bf(Wf[i]);
}

// ---------------- projection: QK = x @ W^T + b, Q pre-scaled ---------------
// One wave per 16-token tile; x read ONCE; all 32 W-tiles streamed (L2-hot).
__global__ __launch_bounds__(256) void k_proj(const float* __restrict__ x,
                                              const u16* __restrict__ Wb,
                                              const float* __restrict__ bias,
                                              u16* __restrict__ Qb,
                                              u16* __restrict__ Kb) {
    const int tid = threadIdx.x, wave = tid >> 6, lane = tid & 63;
    const int l15 = lane & 15, quad = lane >> 4;
    const int tt = blockIdx.x * 4 + wave;              // token tile 0..1023
    const int tbase = tt * 16;

    v8bf a[8];
    const float* xrow = x + (size_t)(tbase + l15) * D_ + quad * 8;
#pragma unroll
    for (int j = 0; j < 8; ++j) {
        float4 f0 = *(const float4*)(xrow + j * 32);
        float4 f1 = *(const float4*)(xrow + j * 32 + 4);
        v8bf t;
        t[0] = (__bf16)f0.x; t[1] = (__bf16)f0.y; t[2] = (__bf16)f0.z; t[3] = (__bf16)f0.w;
        t[4] = (__bf16)f1.x; t[5] = (__bf16)f1.y; t[6] = (__bf16)f1.z; t[7] = (__bf16)f1.w;
        a[j] = t;
    }

    const u16* wbase = Wb + l15 * D_ + quad * 8;
    v8bf wcur[8], wnxt[8];
#pragma unroll
    for (int j = 0; j < 8; ++j) wcur[j] = ldfrag(wbase + j * 32);

    auto tile = [&](const v8bf (&wb)[8], int nt) {
        v4f acc = {0.f, 0.f, 0.f, 0.f};
#pragma unroll
        for (int j = 0; j < 8; ++j)
            acc = __builtin_amdgcn_mfma_f32_16x16x32_bf16(a[j], wb[j], acc, 0, 0, 0);
        const int unit = nt * 16 + l15;
        const float bv = bias[unit];
#pragma unroll
        for (int r = 0; r < 4; ++r) {
            const int tok = tbase + quad * 4 + r;
            const float val = acc[r] + bv;
            if (unit < D_) Qb[tok * D_ + unit] = f2bf(val * SC_);
            else           Kb[tok * D_ + (unit - D_)] = f2bf(val);
        }
    };

    for (int nt = 0; nt < 32; nt += 2) {
        const u16* wp1 = wbase + (nt + 1) * 16 * D_;
#pragma unroll
        for (int j = 0; j < 8; ++j) wnxt[j] = ldfrag(wp1 + j * 32);
        tile(wcur, nt);
        if (nt + 2 < 32) {
            const u16* wp2 = wbase + (nt + 2) * 16 * D_;
#pragma unroll
            for (int j = 0; j < 8; ++j) wcur[j] = ldfrag(wp2 + j * 32);
        }
        tile(wnxt, nt + 1);
    }
}

// ---------------- pass A: Z_q = sum_k exp2(l_scaled) -----------------------
// Stationary: 64 q rows/wave (reg). Streamed: K tiles via LDS ring (32 rows).
__global__ __launch_bounds__(256, 2) void k_passA(const u16* __restrict__ Qb,
                                                  const u16* __restrict__ Kb,
                                                  float* __restrict__ Z) {
    __shared__ u16 sK[2][8192];                 // 2 x 16 KB
    const int tid = threadIdx.x, wave = tid >> 6, lane = tid & 63;
    const int l15 = lane & 15, quad = lane >> 4;
    const int blk = blockIdx.x;                 // 1024
    const int b = blk >> 8, rem = blk & 255;
    const int qg = rem >> 4, ks = rem & 15;     // ks in low bits: XCD-shared stream
    const int qbase = qg * 256 + wave * 64;
    const int kstart = ks * 256;

    v8bf a[4][8];
    {
        const u16* qp = Qb + (size_t)(b * S_ + qbase + l15) * D_ + quad * 8;
#pragma unroll
        for (int s = 0; s < 4; ++s)
#pragma unroll
            for (int j = 0; j < 8; ++j) a[s][j] = ldfrag(qp + s * 16 * D_ + j * 32);
    }
    float z[4][4] = {{0,0,0,0},{0,0,0,0},{0,0,0,0},{0,0,0,0}};

    auto stage = [&](int t, int buf) {
        const u16* src = Kb + (size_t)(b * S_ + kstart + t * 32) * D_;
#pragma unroll
        for (int v = 0; v < 4; ++v) {
            const int idx = v * 256 + wave * 64 + lane;   // 16B chunk id 0..1023
            const int r = idx >> 5, c = idx & 31;
            const int cs = c ^ (r & 7);                    // swizzle on global side
            const u16* gp = src + r * D_ + cs * 8;
            u16* lp = &sK[buf][(v * 256 + wave * 64) * 8]; // wave-uniform base
            __builtin_amdgcn_global_load_lds(AS1C(gp), AS3(lp), 16, 0, 0);
        }
    };

    stage(0, 0);
    for (int t = 0; t < 8; ++t) {
        __syncthreads();                        // drains vmcnt: buf[t&1] ready
        if (t + 1 < 8) stage(t + 1, (t + 1) & 1);
        const u16* base = &sK[t & 1][0];
#pragma unroll
        for (int u = 0; u < 2; ++u) {
            v8bf bf[8];
#pragma unroll
            for (int j = 0; j < 8; ++j) {
                const int cs = (quad + 4 * j) ^ (l15 & 7);
                bf[j] = ldfrag(base + ((u * 16 + l15) * 32 + cs) * 8);
            }
            v4f c0 = {0,0,0,0}, c1 = {0,0,0,0}, c2 = {0,0,0,0}, c3 = {0,0,0,0};
#pragma unroll
            for (int j = 0; j < 8; ++j) {
                c0 = __builtin_amdgcn_mfma_f32_16x16x32_bf16(a[0][j], bf[j], c0, 0, 0, 0);
                c1 = __builtin_amdgcn_mfma_f32_16x16x32_bf16(a[1][j], bf[j], c1, 0, 0, 0);
                c2 = __builtin_amdgcn_mfma_f32_16x16x32_bf16(a[2][j], bf[j], c2, 0, 0, 0);
                c3 = __builtin_amdgcn_mfma_f32_16x16x32_bf16(a[3][j], bf[j], c3, 0, 0, 0);
            }
#pragma unroll
            for (int r = 0; r < 4; ++r) {
                z[0][r] += __builtin_amdgcn_exp2f(c0[r]);
                z[1][r] += __builtin_amdgcn_exp2f(c1[r]);
                z[2][r] += __builtin_amdgcn_exp2f(c2[r]);
                z[3][r] += __builtin_amdgcn_exp2f(c3[r]);
            }
        }
    }

#pragma unroll
    for (int s = 0; s < 4; ++s)
#pragma unroll
        for (int r = 0; r < 4; ++r) {
            float v = z[s][r];
#pragma unroll
            for (int off = 1; off < 16; off <<= 1) v += __shfl_xor(v, off);
            if (l15 == 0) atomicAdd(&Z[b * S_ + qbase + s * 16 + quad * 4 + r], v);
        }
}

// ---------------- reciprocal of Z ----------------
__global__ void k_rcp(const float* __restrict__ Z, float* __restrict__ rZ) {
    int i = blockIdx.x * 256 + threadIdx.x;    // grid 64 -> 16384
    rZ[i] = 1.0f / Z[i];
}

// ---------------- pass B: w_k = sum_q exp2(l_scaled) * rZ_q ----------------
// Stationary: 64 k rows/wave (reg). Streamed: Q tiles via LDS ring (32 rows).
__global__ __launch_bounds__(256, 2) void k_passB(const u16* __restrict__ Qb,
                                                  const u16* __restrict__ Kb,
                                                  const float* __restrict__ rZ,
                                                  float* __restrict__ w) {
    __shared__ u16 sQ[2][8192];
    const int tid = threadIdx.x, wave = tid >> 6, lane = tid & 63;
    const int l15 = lane & 15, quad = lane >> 4;
    const int blk = blockIdx.x;                 // 1024
    const int b = blk >> 8, rem = blk & 255;
    const int kg = rem >> 4, qs = rem & 15;
    const int kbase = kg * 256 + wave * 64;
    const int qstart = qs * 256;

    v8bf bk[4][8];
    {
        const u16* kp = Kb + (size_t)(b * S_ + kbase + l15) * D_ + quad * 8;
#pragma unroll
        for (int s = 0; s < 4; ++s)
#pragma unroll
            for (int j = 0; j < 8; ++j) bk[s][j] = ldfrag(kp + s * 16 * D_ + j * 32);
    }
    float wsum[4] = {0, 0, 0, 0};

    auto stage = [&](int t, int buf) {
        const u16* src = Qb + (size_t)(b * S_ + qstart + t * 32) * D_;
#pragma unroll
        for (int v = 0; v < 4; ++v) {
            const int idx = v * 256 + wave * 64 + lane;
            const int r = idx >> 5, c = idx & 31;
            const int cs = c ^ (r & 7);
            const u16* gp = src + r * D_ + cs * 8;
            u16* lp = &sQ[buf][(v * 256 + wave * 64) * 8];
            __builtin_amdgcn_global_load_lds(AS1C(gp), AS3(lp), 16, 0, 0);
        }
    };

    stage(0, 0);
    const float* zbase = rZ + b * S_ + qstart + quad * 4;
    float4 rz0n = *(const float4*)zbase;
    float4 rz1n = *(const float4*)(zbase + 16);

    for (int t = 0; t < 8; ++t) {
        __syncthreads();
        if (t + 1 < 8) stage(t + 1, (t + 1) & 1);
        const float4 rz0 = rz0n, rz1 = rz1n;
        if (t + 1 < 8) {
            rz0n = *(const float4*)(zbase + (t + 1) * 32);
            rz1n = *(const float4*)(zbase + (t + 1) * 32 + 16);
        }
        const u16* base = &sQ[t & 1][0];
#pragma unroll
        for (int u = 0; u < 2; ++u) {
            v8bf af[8];
#pragma unroll
            for (int j = 0; j < 8; ++j) {
                const int cs = (quad + 4 * j) ^ (l15 & 7);
                af[j] = ldfrag(base + ((u * 16 + l15) * 32 + cs) * 8);
            }
            v4f c0 = {0,0,0,0}, c1 = {0,0,0,0}, c2 = {0,0,0,0}, c3 = {0,0,0,0};
#pragma unroll
            for (int j = 0; j < 8; ++j) {
                c0 = __builtin_amdgcn_mfma_f32_16x16x32_bf16(af[j], bk[0][j], c0, 0, 0, 0);
                c1 = __builtin_amdgcn_mfma_f32_16x16x32_bf16(af[j], bk[1][j], c1, 0, 0, 0);
                c2 = __builtin_amdgcn_mfma_f32_16x16x32_bf16(af[j], bk[2][j], c2, 0, 0, 0);
                c3 = __builtin_amdgcn_mfma_f32_16x16x32_bf16(af[j], bk[3][j], c3, 0, 0, 0);
            }
            const float4 rz = u ? rz1 : rz0;
#pragma unroll
            for (int r = 0; r < 4; ++r) {
                const float rzr = (r == 0) ? rz.x : (r == 1) ? rz.y : (r == 2) ? rz.z : rz.w;
                wsum[0] += __builtin_amdgcn_exp2f(c0[r]) * rzr;
                wsum[1] += __builtin_amdgcn_exp2f(c1[r]) * rzr;
                wsum[2] += __builtin_amdgcn_exp2f(c2[r]) * rzr;
                wsum[3] += __builtin_amdgcn_exp2f(c3[r]) * rzr;
            }
        }
    }

#pragma unroll
    for (int s = 0; s < 4; ++s) {
        wsum[s] += __shfl_xor(wsum[s], 16);
        wsum[s] += __shfl_xor(wsum[s], 32);
        if (quad == 0) atomicAdd(&w[b * S_ + kbase + s * 16 + l15], wsum[s]);
    }
}

// ---------------- final: out[b,d] = sum_k w[b,k] * x[b,k,d] ----------------
__global__ __launch_bounds__(256) void k_final(const float* __restrict__ x,
                                               const float* __restrict__ w,
                                               float* __restrict__ out) {
    const int b = blockIdx.x >> 7, kc = blockIdx.x & 127;  // grid 512
    const int d = threadIdx.x;
    const int k0 = kc * 32;
    float acc = 0.f;
    const float* xp = x + (size_t)(b * S_ + k0) * D_ + d;
    const float* wp = w + b * S_ + k0;
#pragma unroll 8
    for (int kk = 0; kk < 32; ++kk) acc += wp[kk] * xp[(size_t)kk * D_];
    atomicAdd(&out[b * D_ + d], acc);
}

extern "C" void kernel_launch(void* const* d_in, const int* in_sizes, int n_in,
                              void* d_out, int out_size, void* d_ws, size_t ws_size,
                              hipStream_t stream) {
    const float* x    = (const float*)d_in[0];   // [4,4096,256]
    const float* W    = (const float*)d_in[1];   // [512,256]
    const float* bias = (const float*)d_in[2];   // [512]
    float* out = (float*)d_out;                  // [4,256]

    char* ws = (char*)d_ws;
    u16*   Qb = (u16*)ws;                                 //  8 MiB
    u16*   Kb = Qb + (size_t)B_ * S_ * D_;                //  8 MiB
    float* Z  = (float*)(ws + 16777216);                  // 64 KiB
    float* rZ = Z + B_ * S_;                              // 64 KiB
    float* w  = rZ + B_ * S_;                             // 64 KiB
    u16*   Wb = (u16*)(w + B_ * S_);                      // 256 KiB

    hipMemsetAsync(Z, 0, 3 * B_ * S_ * sizeof(float), stream);  // Z, rZ, w
    hipMemsetAsync(out, 0, B_ * D_ * sizeof(float), stream);

    k_convw<<<E_ * D_ / 256, 256, 0, stream>>>(W, Wb);
    k_proj <<<256, 256, 0, stream>>>(x, Wb, bias, Qb, Kb);
    k_passA<<<1024, 256, 0, stream>>>(Qb, Kb, Z);
    k_rcp  <<<B_ * S_ / 256, 256, 0, stream>>>(Z, rZ);
    k_passB<<<1024, 256, 0, stream>>>(Qb, Kb, rZ, w);
    k_final<<<512, 256, 0, stream>>>(x, w, out);
}

// Round 5
// 223.820 us; speedup vs baseline: 1.6165x; 1.0104x over previous
//
#include <hip/hip_runtime.h>
#include <stdint.h>

typedef __bf16 v8bf __attribute__((ext_vector_type(8)));
typedef float  v4f  __attribute__((ext_vector_type(4)));
typedef int    v4i  __attribute__((ext_vector_type(4)));
typedef unsigned short u16;
typedef unsigned char  u8;

static constexpr int B_ = 4, S_ = 4096, D_ = 256, E_ = 512;
// i8 symmetric quant: clip 4.8 (~5.9 sigma of q/k), Delta = 4.8/127
static constexpr float QSC_ = 127.0f / 4.8f;          // quant scale
static constexpr float DQ_  = 1.288045e-4f;           // Delta^2 * (1/16) * log2(e)

#define AS1C(p) ((const __attribute__((address_space(1))) void*)(p))
#define AS3(p)  ((__attribute__((address_space(3))) void*)(p))

__device__ __forceinline__ v8bf ldfrag(const u16* p) {
    return __builtin_bit_cast(v8bf, *(const uint4*)p);
}
__device__ __forceinline__ u16 f2bf(float f) {
    return __builtin_bit_cast(u16, (__bf16)f);
}
__device__ __forceinline__ u8 f2i8(float f) {
    float t = fminf(fmaxf(f * QSC_, -127.f), 127.f);
    return (u8)(signed char)__float2int_rn(t);
}

// ---------------- W fp32 -> bf16, plus zero-init of Z/w/out ----------------
__global__ void k_convw(const float* __restrict__ Wf, u16* __restrict__ Wb,
                        float* __restrict__ Z, float* __restrict__ w,
                        float* __restrict__ out) {
    int i = blockIdx.x * 256 + threadIdx.x;           // grid 512 -> 131072
    Wb[i] = f2bf(Wf[i]);
    if (i < B_ * S_) { Z[i] = 0.f; w[i] = 0.f; }
    if (i < B_ * D_) out[i] = 0.f;
}

// ---------------- projection: QK = x @ W^T + b -> i8 Q,K -------------------
// 2 waves per token tile: parity 0 waves produce Q (units 0..255),
// parity 1 waves produce K (units 256..511). Grid 512 = 2 blocks/CU.
__global__ __launch_bounds__(256) void k_proj(const float* __restrict__ x,
                                              const u16* __restrict__ Wb,
                                              const float* __restrict__ bias,
                                              u8* __restrict__ Qi,
                                              u8* __restrict__ Ki) {
    const int tid = threadIdx.x, wave = tid >> 6, lane = tid & 63;
    const int l15 = lane & 15, quad = lane >> 4;
    const int tt = blockIdx.x * 2 + (wave >> 1);       // token tile 0..1023
    const int wsel = wave & 1;                         // 0 -> Q, 1 -> K
    const int tbase = tt * 16;

    v8bf a[8];
    const float* xrow = x + (size_t)(tbase + l15) * D_ + quad * 8;
#pragma unroll
    for (int j = 0; j < 8; ++j) {
        float4 f0 = *(const float4*)(xrow + j * 32);
        float4 f1 = *(const float4*)(xrow + j * 32 + 4);
        v8bf t;
        t[0] = (__bf16)f0.x; t[1] = (__bf16)f0.y; t[2] = (__bf16)f0.z; t[3] = (__bf16)f0.w;
        t[4] = (__bf16)f1.x; t[5] = (__bf16)f1.y; t[6] = (__bf16)f1.z; t[7] = (__bf16)f1.w;
        a[j] = t;
    }

    u8* dst = wsel ? Ki : Qi;
    const u16* wbase = Wb + (size_t)(wsel * 256 + l15) * D_ + quad * 8;
    const float* bb = bias + wsel * 256;

    v8bf wcur[8], wnxt[8];
#pragma unroll
    for (int j = 0; j < 8; ++j) wcur[j] = ldfrag(wbase + j * 32);

    auto tile = [&](const v8bf (&wb)[8], int nt) {
        v4f acc = {0.f, 0.f, 0.f, 0.f};
#pragma unroll
        for (int j = 0; j < 8; ++j)
            acc = __builtin_amdgcn_mfma_f32_16x16x32_bf16(a[j], wb[j], acc, 0, 0, 0);
        const int col = nt * 16 + l15;                 // 0..255 within Q or K
        const float bv = bb[col];
#pragma unroll
        for (int r = 0; r < 4; ++r) {
            const int tok = tbase + quad * 4 + r;
            dst[tok * D_ + col] = f2i8(acc[r] + bv);
        }
    };

    for (int nt = 0; nt < 16; nt += 2) {
        const u16* wp1 = wbase + (size_t)(nt + 1) * 16 * D_;
#pragma unroll
        for (int j = 0; j < 8; ++j) wnxt[j] = ldfrag(wp1 + j * 32);
        tile(wcur, nt);
        if (nt + 2 < 16) {
            const u16* wp2 = wbase + (size_t)(nt + 2) * 16 * D_;
#pragma unroll
            for (int j = 0; j < 8; ++j) wcur[j] = ldfrag(wp2 + j * 32);
        }
        tile(wnxt, nt + 1);
    }
}

// Stage a 64-row x 256B i8 tile into LDS (16 KB), XOR-swizzled:
// LDS slot (R,P) holds global chunk c = P ^ (R&15). Read side: fragment
// (kc,quad) of row l15 lives at P = (kc*4+quad) ^ l15 -> uniform bank spread.
__device__ __forceinline__ void stage64(const u8* src, u8* dst,
                                        int wave, int lane) {
#pragma unroll
    for (int v = 0; v < 4; ++v) {
        const int sbase = v * 256 + wave * 64;         // wave-uniform slot base
        const int slot = sbase + lane;
        const int R = slot >> 4, P = slot & 15;
        const int c = P ^ (R & 15);
        __builtin_amdgcn_global_load_lds(AS1C(src + R * 256 + c * 16),
                                         AS3(dst + sbase * 16), 16, 0, 0);
    }
}

// ---------------- pass A: Z_q = sum_k exp2(dot_i32 * DQ) -------------------
// Stationary: 128 q rows/wave (8 sets, 128 VGPRs). Streamed: 4 x 64-key tiles.
__global__ __launch_bounds__(256, 2) void k_passA(const u8* __restrict__ Qi,
                                                  const u8* __restrict__ Ki,
                                                  float* __restrict__ Z) {
    __shared__ u8 sK[2][16384];
    const int tid = threadIdx.x, wave = tid >> 6, lane = tid & 63;
    const int l15 = lane & 15, quad = lane >> 4;
    const int blk = blockIdx.x;                 // 512 = b(4) x qg(8) x ks(16)
    const int ks = blk & 15;                    // low bits -> XCD-spread streams
    const int qg = (blk >> 4) & 7;
    const int b = blk >> 7;
    const int qbase = qg * 512 + wave * 128;
    const int kstart = ks * 256;

    v4i a[8][4];
    {
        const u8* qp = Qi + (size_t)(b * S_ + qbase + l15) * D_ + quad * 16;
#pragma unroll
        for (int s = 0; s < 8; ++s)
#pragma unroll
            for (int c = 0; c < 4; ++c)
                a[s][c] = *(const v4i*)(qp + s * 16 * D_ + c * 64);
    }
    float z[8][4];
#pragma unroll
    for (int s = 0; s < 8; ++s)
#pragma unroll
        for (int r = 0; r < 4; ++r) z[s][r] = 0.f;

    const u8* kb = Ki + (size_t)(b * S_ + kstart) * D_;
    stage64(kb, sK[0], wave, lane);

    for (int t = 0; t < 4; ++t) {
        __syncthreads();
        if (t + 1 < 4) stage64(kb + (size_t)(t + 1) * 64 * D_, sK[(t + 1) & 1], wave, lane);
        const u8* base = sK[t & 1];
#pragma unroll
        for (int u = 0; u < 4; ++u) {          // 4 subtiles of 16 keys
            v4i bf[4];
#pragma unroll
            for (int kc = 0; kc < 4; ++kc) {
                const int P = (kc * 4 + quad) ^ l15;
                bf[kc] = *(const v4i*)(base + (u * 16 + l15) * 256 + P * 16);
            }
            v4i c0 = {0,0,0,0}, c1 = {0,0,0,0}, c2 = {0,0,0,0}, c3 = {0,0,0,0};
            v4i c4 = {0,0,0,0}, c5 = {0,0,0,0}, c6 = {0,0,0,0}, c7 = {0,0,0,0};
#pragma unroll
            for (int kc = 0; kc < 4; ++kc) {
                c0 = __builtin_amdgcn_mfma_i32_16x16x64_i8(a[0][kc], bf[kc], c0, 0, 0, 0);
                c1 = __builtin_amdgcn_mfma_i32_16x16x64_i8(a[1][kc], bf[kc], c1, 0, 0, 0);
                c2 = __builtin_amdgcn_mfma_i32_16x16x64_i8(a[2][kc], bf[kc], c2, 0, 0, 0);
                c3 = __builtin_amdgcn_mfma_i32_16x16x64_i8(a[3][kc], bf[kc], c3, 0, 0, 0);
                c4 = __builtin_amdgcn_mfma_i32_16x16x64_i8(a[4][kc], bf[kc], c4, 0, 0, 0);
                c5 = __builtin_amdgcn_mfma_i32_16x16x64_i8(a[5][kc], bf[kc], c5, 0, 0, 0);
                c6 = __builtin_amdgcn_mfma_i32_16x16x64_i8(a[6][kc], bf[kc], c6, 0, 0, 0);
                c7 = __builtin_amdgcn_mfma_i32_16x16x64_i8(a[7][kc], bf[kc], c7, 0, 0, 0);
            }
#pragma unroll
            for (int r = 0; r < 4; ++r) {
                z[0][r] += __builtin_amdgcn_exp2f((float)c0[r] * DQ_);
                z[1][r] += __builtin_amdgcn_exp2f((float)c1[r] * DQ_);
                z[2][r] += __builtin_amdgcn_exp2f((float)c2[r] * DQ_);
                z[3][r] += __builtin_amdgcn_exp2f((float)c3[r] * DQ_);
                z[4][r] += __builtin_amdgcn_exp2f((float)c4[r] * DQ_);
                z[5][r] += __builtin_amdgcn_exp2f((float)c5[r] * DQ_);
                z[6][r] += __builtin_amdgcn_exp2f((float)c6[r] * DQ_);
                z[7][r] += __builtin_amdgcn_exp2f((float)c7[r] * DQ_);
            }
        }
    }

#pragma unroll
    for (int s = 0; s < 8; ++s)
#pragma unroll
        for (int r = 0; r < 4; ++r) {
            float v = z[s][r];
#pragma unroll
            for (int off = 1; off < 16; off <<= 1) v += __shfl_xor(v, off);
            if (l15 == 0) atomicAdd(&Z[b * S_ + qbase + s * 16 + quad * 4 + r], v);
        }
}

// ---------------- pass B: w_k = sum_q exp2(dot_i32 * DQ) / Z_q -------------
// Stationary: 128 k rows/wave (8 sets). Streamed: 4 x 64-query tiles + Z.
__global__ __launch_bounds__(256, 2) void k_passB(const u8* __restrict__ Qi,
                                                  const u8* __restrict__ Ki,
                                                  const float* __restrict__ Zs,
                                                  float* __restrict__ w) {
    __shared__ u8 sQ[2][16384];
    const int tid = threadIdx.x, wave = tid >> 6, lane = tid & 63;
    const int l15 = lane & 15, quad = lane >> 4;
    const int blk = blockIdx.x;                 // 512 = b(4) x kg(8) x qs(16)
    const int qs = blk & 15;
    const int kg = (blk >> 4) & 7;
    const int b = blk >> 7;
    const int kbase = kg * 512 + wave * 128;
    const int qstart = qs * 256;

    v4i bk[8][4];
    {
        const u8* kp = Ki + (size_t)(b * S_ + kbase + l15) * D_ + quad * 16;
#pragma unroll
        for (int s = 0; s < 8; ++s)
#pragma unroll
            for (int c = 0; c < 4; ++c)
                bk[s][c] = *(const v4i*)(kp + s * 16 * D_ + c * 64);
    }
    float wsum[8];
#pragma unroll
    for (int s = 0; s < 8; ++s) wsum[s] = 0.f;

    const u8* qb = Qi + (size_t)(b * S_ + qstart) * D_;
    stage64(qb, sQ[0], wave, lane);
    const float* zrow = Zs + b * S_ + qstart + quad * 4;

    for (int t = 0; t < 4; ++t) {
        __syncthreads();
        if (t + 1 < 4) stage64(qb + (size_t)(t + 1) * 64 * D_, sQ[(t + 1) & 1], wave, lane);
        const u8* base = sQ[t & 1];
#pragma unroll
        for (int u = 0; u < 4; ++u) {          // 4 subtiles of 16 queries
            const float4 Zv = *(const float4*)(zrow + t * 64 + u * 16);
            v4i af[4];
#pragma unroll
            for (int kc = 0; kc < 4; ++kc) {
                const int P = (kc * 4 + quad) ^ l15;
                af[kc] = *(const v4i*)(base + (u * 16 + l15) * 256 + P * 16);
            }
            v4i c0 = {0,0,0,0}, c1 = {0,0,0,0}, c2 = {0,0,0,0}, c3 = {0,0,0,0};
            v4i c4 = {0,0,0,0}, c5 = {0,0,0,0}, c6 = {0,0,0,0}, c7 = {0,0,0,0};
#pragma unroll
            for (int kc = 0; kc < 4; ++kc) {
                c0 = __builtin_amdgcn_mfma_i32_16x16x64_i8(af[kc], bk[0][kc], c0, 0, 0, 0);
                c1 = __builtin_amdgcn_mfma_i32_16x16x64_i8(af[kc], bk[1][kc], c1, 0, 0, 0);
                c2 = __builtin_amdgcn_mfma_i32_16x16x64_i8(af[kc], bk[2][kc], c2, 0, 0, 0);
                c3 = __builtin_amdgcn_mfma_i32_16x16x64_i8(af[kc], bk[3][kc], c3, 0, 0, 0);
                c4 = __builtin_amdgcn_mfma_i32_16x16x64_i8(af[kc], bk[4][kc], c4, 0, 0, 0);
                c5 = __builtin_amdgcn_mfma_i32_16x16x64_i8(af[kc], bk[5][kc], c5, 0, 0, 0);
                c6 = __builtin_amdgcn_mfma_i32_16x16x64_i8(af[kc], bk[6][kc], c6, 0, 0, 0);
                c7 = __builtin_amdgcn_mfma_i32_16x16x64_i8(af[kc], bk[7][kc], c7, 0, 0, 0);
            }
            const float rz0 = __builtin_amdgcn_rcpf(Zv.x);
            const float rz1 = __builtin_amdgcn_rcpf(Zv.y);
            const float rz2 = __builtin_amdgcn_rcpf(Zv.z);
            const float rz3 = __builtin_amdgcn_rcpf(Zv.w);
            wsum[0] += __builtin_amdgcn_exp2f((float)c0[0] * DQ_) * rz0 + __builtin_amdgcn_exp2f((float)c0[1] * DQ_) * rz1
                     + __builtin_amdgcn_exp2f((float)c0[2] * DQ_) * rz2 + __builtin_amdgcn_exp2f((float)c0[3] * DQ_) * rz3;
            wsum[1] += __builtin_amdgcn_exp2f((float)c1[0] * DQ_) * rz0 + __builtin_amdgcn_exp2f((float)c1[1] * DQ_) * rz1
                     + __builtin_amdgcn_exp2f((float)c1[2] * DQ_) * rz2 + __builtin_amdgcn_exp2f((float)c1[3] * DQ_) * rz3;
            wsum[2] += __builtin_amdgcn_exp2f((float)c2[0] * DQ_) * rz0 + __builtin_amdgcn_exp2f((float)c2[1] * DQ_) * rz1
                     + __builtin_amdgcn_exp2f((float)c2[2] * DQ_) * rz2 + __builtin_amdgcn_exp2f((float)c2[3] * DQ_) * rz3;
            wsum[3] += __builtin_amdgcn_exp2f((float)c3[0] * DQ_) * rz0 + __builtin_amdgcn_exp2f((float)c3[1] * DQ_) * rz1
                     + __builtin_amdgcn_exp2f((float)c3[2] * DQ_) * rz2 + __builtin_amdgcn_exp2f((float)c3[3] * DQ_) * rz3;
            wsum[4] += __builtin_amdgcn_exp2f((float)c4[0] * DQ_) * rz0 + __builtin_amdgcn_exp2f((float)c4[1] * DQ_) * rz1
                     + __builtin_amdgcn_exp2f((float)c4[2] * DQ_) * rz2 + __builtin_amdgcn_exp2f((float)c4[3] * DQ_) * rz3;
            wsum[5] += __builtin_amdgcn_exp2f((float)c5[0] * DQ_) * rz0 + __builtin_amdgcn_exp2f((float)c5[1] * DQ_) * rz1
                     + __builtin_amdgcn_exp2f((float)c5[2] * DQ_) * rz2 + __builtin_amdgcn_exp2f((float)c5[3] * DQ_) * rz3;
            wsum[6] += __builtin_amdgcn_exp2f((float)c6[0] * DQ_) * rz0 + __builtin_amdgcn_exp2f((float)c6[1] * DQ_) * rz1
                     + __builtin_amdgcn_exp2f((float)c6[2] * DQ_) * rz2 + __builtin_amdgcn_exp2f((float)c6[3] * DQ_) * rz3;
            wsum[7] += __builtin_amdgcn_exp2f((float)c7[0] * DQ_) * rz0 + __builtin_amdgcn_exp2f((float)c7[1] * DQ_) * rz1
                     + __builtin_amdgcn_exp2f((float)c7[2] * DQ_) * rz2 + __builtin_amdgcn_exp2f((float)c7[3] * DQ_) * rz3;
        }
    }

#pragma unroll
    for (int s = 0; s < 8; ++s) {
        wsum[s] += __shfl_xor(wsum[s], 16);
        wsum[s] += __shfl_xor(wsum[s], 32);
        if (quad == 0) atomicAdd(&w[b * S_ + kbase + s * 16 + l15], wsum[s]);
    }
}

// ---------------- final: out[b,d] = sum_k w[b,k] * x[b,k,d] ----------------
__global__ __launch_bounds__(256) void k_final(const float* __restrict__ x,
                                               const float* __restrict__ w,
                                               float* __restrict__ out) {
    const int b = blockIdx.x >> 7, kc = blockIdx.x & 127;  // grid 512
    const int d = threadIdx.x;
    const int k0 = kc * 32;
    float acc = 0.f;
    const float* xp = x + (size_t)(b * S_ + k0) * D_ + d;
    const float* wp = w + b * S_ + k0;
#pragma unroll 8
    for (int kk = 0; kk < 32; ++kk) acc += wp[kk] * xp[(size_t)kk * D_];
    atomicAdd(&out[b * D_ + d], acc);
}

extern "C" void kernel_launch(void* const* d_in, const int* in_sizes, int n_in,
                              void* d_out, int out_size, void* d_ws, size_t ws_size,
                              hipStream_t stream) {
    const float* x    = (const float*)d_in[0];   // [4,4096,256]
    const float* W    = (const float*)d_in[1];   // [512,256]
    const float* bias = (const float*)d_in[2];   // [512]
    float* out = (float*)d_out;                  // [4,256]

    char* ws = (char*)d_ws;
    u8*    Qi = (u8*)ws;                                  // 4 MiB
    u8*    Ki = Qi + (size_t)B_ * S_ * D_;                // 4 MiB
    float* Z  = (float*)(ws + 8388608);                   // 64 KiB
    float* w  = Z + B_ * S_;                              // 64 KiB
    u16*   Wb = (u16*)(w + B_ * S_);                      // 256 KiB

    k_convw<<<E_ * D_ / 256, 256, 0, stream>>>(W, Wb, Z, w, out);
    k_proj <<<512, 256, 0, stream>>>(x, Wb, bias, Qi, Ki);
    k_passA<<<512, 256, 0, stream>>>(Qi, Ki, Z);
    k_passB<<<512, 256, 0, stream>>>(Qi, Ki, Z, w);
    k_final<<<512, 256, 0, stream>>>(x, w, out);
}

// Round 6
// 155.474 us; speedup vs baseline: 2.3272x; 1.4396x over previous
//
#include <hip/hip_runtime.h>
#include <stdint.h>

typedef __bf16 v8bf __attribute__((ext_vector_type(8)));
typedef float  v4f  __attribute__((ext_vector_type(4)));
typedef int    v4i  __attribute__((ext_vector_type(4)));
typedef unsigned short u16;
typedef unsigned char  u8;

static constexpr int B_ = 4, S_ = 4096, D_ = 256, E_ = 512;
// i8 symmetric quant: clip 4.8 (~5.9 sigma of q/k), Delta = 4.8/127
static constexpr float QSC_ = 127.0f / 4.8f;          // quant scale
static constexpr float DQ_  = 1.288045e-4f;           // Delta^2 * (1/16) * log2(e)

#define AS1C(p) ((const __attribute__((address_space(1))) void*)(p))
#define AS3(p)  ((__attribute__((address_space(3))) void*)(p))

__device__ __forceinline__ v8bf ldfrag(const u16* p) {
    return __builtin_bit_cast(v8bf, *(const uint4*)p);
}
__device__ __forceinline__ u16 f2bf(float f) {
    return __builtin_bit_cast(u16, (__bf16)f);
}
__device__ __forceinline__ u8 f2i8(float f) {
    float t = fminf(fmaxf(f * QSC_, -127.f), 127.f);
    return (u8)(signed char)__float2int_rn(t);
}

// ---------------- W fp32 -> bf16, plus zero-init of Z/w/out ----------------
__global__ void k_convw(const float* __restrict__ Wf, u16* __restrict__ Wb,
                        float* __restrict__ Z, float* __restrict__ w,
                        float* __restrict__ out) {
    int i = blockIdx.x * 256 + threadIdx.x;           // grid 512 -> 131072
    Wb[i] = f2bf(Wf[i]);
    if (i < B_ * S_) { Z[i] = 0.f; w[i] = 0.f; }
    if (i < B_ * D_) out[i] = 0.f;
}

// ---------------- projection: QK = x @ W^T + b -> i8 Q,K -------------------
__global__ __launch_bounds__(256) void k_proj(const float* __restrict__ x,
                                              const u16* __restrict__ Wb,
                                              const float* __restrict__ bias,
                                              u8* __restrict__ Qi,
                                              u8* __restrict__ Ki) {
    const int tid = threadIdx.x, wave = tid >> 6, lane = tid & 63;
    const int l15 = lane & 15, quad = lane >> 4;
    const int tt = blockIdx.x * 2 + (wave >> 1);       // token tile 0..1023
    const int wsel = wave & 1;                         // 0 -> Q, 1 -> K
    const int tbase = tt * 16;

    v8bf a[8];
    const float* xrow = x + (size_t)(tbase + l15) * D_ + quad * 8;
#pragma unroll
    for (int j = 0; j < 8; ++j) {
        float4 f0 = *(const float4*)(xrow + j * 32);
        float4 f1 = *(const float4*)(xrow + j * 32 + 4);
        v8bf t;
        t[0] = (__bf16)f0.x; t[1] = (__bf16)f0.y; t[2] = (__bf16)f0.z; t[3] = (__bf16)f0.w;
        t[4] = (__bf16)f1.x; t[5] = (__bf16)f1.y; t[6] = (__bf16)f1.z; t[7] = (__bf16)f1.w;
        a[j] = t;
    }

    u8* dst = wsel ? Ki : Qi;
    const u16* wbase = Wb + (size_t)(wsel * 256 + l15) * D_ + quad * 8;
    const float* bb = bias + wsel * 256;

    v8bf wcur[8], wnxt[8];
#pragma unroll
    for (int j = 0; j < 8; ++j) wcur[j] = ldfrag(wbase + j * 32);

    auto tile = [&](const v8bf (&wb)[8], int nt) {
        v4f acc = {0.f, 0.f, 0.f, 0.f};
#pragma unroll
        for (int j = 0; j < 8; ++j)
            acc = __builtin_amdgcn_mfma_f32_16x16x32_bf16(a[j], wb[j], acc, 0, 0, 0);
        const int col = nt * 16 + l15;                 // 0..255 within Q or K
        const float bv = bb[col];
#pragma unroll
        for (int r = 0; r < 4; ++r) {
            const int tok = tbase + quad * 4 + r;
            dst[tok * D_ + col] = f2i8(acc[r] + bv);
        }
    };

    for (int nt = 0; nt < 16; nt += 2) {
        const u16* wp1 = wbase + (size_t)(nt + 1) * 16 * D_;
#pragma unroll
        for (int j = 0; j < 8; ++j) wnxt[j] = ldfrag(wp1 + j * 32);
        tile(wcur, nt);
        if (nt + 2 < 16) {
            const u16* wp2 = wbase + (size_t)(nt + 2) * 16 * D_;
#pragma unroll
            for (int j = 0; j < 8; ++j) wcur[j] = ldfrag(wp2 + j * 32);
        }
        tile(wnxt, nt + 1);
    }
}

// Stage a 64-row x 256B i8 tile into LDS (16 KB), XOR-swizzled:
// LDS slot (R,P) holds global chunk c = P ^ (R&15). Read side: fragment
// (kc,quad) of row l15 lives at P = (kc*4+quad) ^ l15 -> uniform bank spread.
// [verified round 5: SQ_LDS_BANK_CONFLICT == 0]
__device__ __forceinline__ void stage64(const u8* src, u8* dst,
                                        int wave, int lane) {
#pragma unroll
    for (int v = 0; v < 4; ++v) {
        const int sbase = v * 256 + wave * 64;         // wave-uniform slot base
        const int slot = sbase + lane;
        const int R = slot >> 4, P = slot & 15;
        const int c = P ^ (R & 15);
        __builtin_amdgcn_global_load_lds(AS1C(src + R * 256 + c * 16),
                                         AS3(dst + sbase * 16), 16, 0, 0);
    }
}

// ---------------- pass A: Z_q = sum_k exp2(dot_i32 * DQ) -------------------
// Stationary: 64 q rows/wave (4 sets, 64 VGPRs — spill-safe). Streamed:
// 8 x 64-key tiles via LDS ring. XCD = blk%8 = ks -> K stream L2-pinned.
__global__ __launch_bounds__(256, 2) void k_passA(const u8* __restrict__ Qi,
                                                  const u8* __restrict__ Ki,
                                                  float* __restrict__ Z) {
    __shared__ u8 sK[2][16384];
    const int tid = threadIdx.x, wave = tid >> 6, lane = tid & 63;
    const int l15 = lane & 15, quad = lane >> 4;
    const int blk = blockIdx.x;                 // 512 = b(4) x qg(16) x ks(8)
    const int ks = blk & 7;
    const int qg = (blk >> 3) & 15;
    const int b = blk >> 7;
    const int qbase = qg * 256 + wave * 64;
    const int kstart = ks * 512;

    v4i a[4][4];
    {
        const u8* qp = Qi + (size_t)(b * S_ + qbase + l15) * D_ + quad * 16;
#pragma unroll
        for (int s = 0; s < 4; ++s)
#pragma unroll
            for (int c = 0; c < 4; ++c)
                a[s][c] = *(const v4i*)(qp + s * 16 * D_ + c * 64);
    }
    float z[4][4];
#pragma unroll
    for (int s = 0; s < 4; ++s)
#pragma unroll
        for (int r = 0; r < 4; ++r) z[s][r] = 0.f;

    const u8* kb = Ki + (size_t)(b * S_ + kstart) * D_;
    stage64(kb, sK[0], wave, lane);

    for (int t = 0; t < 8; ++t) {
        __syncthreads();
        if (t + 1 < 8) stage64(kb + (size_t)(t + 1) * 64 * D_, sK[(t + 1) & 1], wave, lane);
        const u8* base = sK[t & 1];
#pragma unroll
        for (int u = 0; u < 4; ++u) {          // 4 subtiles of 16 keys
            v4i bf[4];
#pragma unroll
            for (int kc = 0; kc < 4; ++kc) {
                const int P = (kc * 4 + quad) ^ l15;
                bf[kc] = *(const v4i*)(base + (u * 16 + l15) * 256 + P * 16);
            }
            v4i c0 = {0,0,0,0}, c1 = {0,0,0,0}, c2 = {0,0,0,0}, c3 = {0,0,0,0};
#pragma unroll
            for (int kc = 0; kc < 4; ++kc) {
                c0 = __builtin_amdgcn_mfma_i32_16x16x64_i8(a[0][kc], bf[kc], c0, 0, 0, 0);
                c1 = __builtin_amdgcn_mfma_i32_16x16x64_i8(a[1][kc], bf[kc], c1, 0, 0, 0);
                c2 = __builtin_amdgcn_mfma_i32_16x16x64_i8(a[2][kc], bf[kc], c2, 0, 0, 0);
                c3 = __builtin_amdgcn_mfma_i32_16x16x64_i8(a[3][kc], bf[kc], c3, 0, 0, 0);
            }
#pragma unroll
            for (int r = 0; r < 4; ++r) {
                z[0][r] += __builtin_amdgcn_exp2f((float)c0[r] * DQ_);
                z[1][r] += __builtin_amdgcn_exp2f((float)c1[r] * DQ_);
                z[2][r] += __builtin_amdgcn_exp2f((float)c2[r] * DQ_);
                z[3][r] += __builtin_amdgcn_exp2f((float)c3[r] * DQ_);
            }
        }
    }

#pragma unroll
    for (int s = 0; s < 4; ++s)
#pragma unroll
        for (int r = 0; r < 4; ++r) {
            float v = z[s][r];
#pragma unroll
            for (int off = 1; off < 16; off <<= 1) v += __shfl_xor(v, off);
            if (l15 == 0) atomicAdd(&Z[b * S_ + qbase + s * 16 + quad * 4 + r], v);
        }
}

// ---------------- pass B: w_k = sum_q exp2(dot_i32 * DQ) / Z_q -------------
// Stationary: 64 k rows/wave (4 sets). Streamed: 8 x 64-query tiles + Z.
__global__ __launch_bounds__(256, 2) void k_passB(const u8* __restrict__ Qi,
                                                  const u8* __restrict__ Ki,
                                                  const float* __restrict__ Zs,
                                                  float* __restrict__ w) {
    __shared__ u8 sQ[2][16384];
    const int tid = threadIdx.x, wave = tid >> 6, lane = tid & 63;
    const int l15 = lane & 15, quad = lane >> 4;
    const int blk = blockIdx.x;                 // 512 = b(4) x kg(16) x qs(8)
    const int qs = blk & 7;
    const int kg = (blk >> 3) & 15;
    const int b = blk >> 7;
    const int kbase = kg * 256 + wave * 64;
    const int qstart = qs * 512;

    v4i bk[4][4];
    {
        const u8* kp = Ki + (size_t)(b * S_ + kbase + l15) * D_ + quad * 16;
#pragma unroll
        for (int s = 0; s < 4; ++s)
#pragma unroll
            for (int c = 0; c < 4; ++c)
                bk[s][c] = *(const v4i*)(kp + s * 16 * D_ + c * 64);
    }
    float wsum[4] = {0.f, 0.f, 0.f, 0.f};

    const u8* qb = Qi + (size_t)(b * S_ + qstart) * D_;
    stage64(qb, sQ[0], wave, lane);
    const float* zrow = Zs + b * S_ + qstart + quad * 4;

    for (int t = 0; t < 8; ++t) {
        __syncthreads();
        if (t + 1 < 8) stage64(qb + (size_t)(t + 1) * 64 * D_, sQ[(t + 1) & 1], wave, lane);
        const u8* base = sQ[t & 1];
#pragma unroll
        for (int u = 0; u < 4; ++u) {          // 4 subtiles of 16 queries
            const float4 Zv = *(const float4*)(zrow + t * 64 + u * 16);
            v4i af[4];
#pragma unroll
            for (int kc = 0; kc < 4; ++kc) {
                const int P = (kc * 4 + quad) ^ l15;
                af[kc] = *(const v4i*)(base + (u * 16 + l15) * 256 + P * 16);
            }
            v4i c0 = {0,0,0,0}, c1 = {0,0,0,0}, c2 = {0,0,0,0}, c3 = {0,0,0,0};
#pragma unroll
            for (int kc = 0; kc < 4; ++kc) {
                c0 = __builtin_amdgcn_mfma_i32_16x16x64_i8(af[kc], bk[0][kc], c0, 0, 0, 0);
                c1 = __builtin_amdgcn_mfma_i32_16x16x64_i8(af[kc], bk[1][kc], c1, 0, 0, 0);
                c2 = __builtin_amdgcn_mfma_i32_16x16x64_i8(af[kc], bk[2][kc], c2, 0, 0, 0);
                c3 = __builtin_amdgcn_mfma_i32_16x16x64_i8(af[kc], bk[3][kc], c3, 0, 0, 0);
            }
            const float rz0 = __builtin_amdgcn_rcpf(Zv.x);
            const float rz1 = __builtin_amdgcn_rcpf(Zv.y);
            const float rz2 = __builtin_amdgcn_rcpf(Zv.z);
            const float rz3 = __builtin_amdgcn_rcpf(Zv.w);
            wsum[0] += __builtin_amdgcn_exp2f((float)c0[0] * DQ_) * rz0 + __builtin_amdgcn_exp2f((float)c0[1] * DQ_) * rz1
                     + __builtin_amdgcn_exp2f((float)c0[2] * DQ_) * rz2 + __builtin_amdgcn_exp2f((float)c0[3] * DQ_) * rz3;
            wsum[1] += __builtin_amdgcn_exp2f((float)c1[0] * DQ_) * rz0 + __builtin_amdgcn_exp2f((float)c1[1] * DQ_) * rz1
                     + __builtin_amdgcn_exp2f((float)c1[2] * DQ_) * rz2 + __builtin_amdgcn_exp2f((float)c1[3] * DQ_) * rz3;
            wsum[2] += __builtin_amdgcn_exp2f((float)c2[0] * DQ_) * rz0 + __builtin_amdgcn_exp2f((float)c2[1] * DQ_) * rz1
                     + __builtin_amdgcn_exp2f((float)c2[2] * DQ_) * rz2 + __builtin_amdgcn_exp2f((float)c2[3] * DQ_) * rz3;
            wsum[3] += __builtin_amdgcn_exp2f((float)c3[0] * DQ_) * rz0 + __builtin_amdgcn_exp2f((float)c3[1] * DQ_) * rz1
                     + __builtin_amdgcn_exp2f((float)c3[2] * DQ_) * rz2 + __builtin_amdgcn_exp2f((float)c3[3] * DQ_) * rz3;
        }
    }

#pragma unroll
    for (int s = 0; s < 4; ++s) {
        wsum[s] += __shfl_xor(wsum[s], 16);
        wsum[s] += __shfl_xor(wsum[s], 32);
        if (quad == 0) atomicAdd(&w[b * S_ + kbase + s * 16 + l15], wsum[s]);
    }
}

// ---------------- final: out[b,d] = sum_k w[b,k] * x[b,k,d] ----------------
__global__ __launch_bounds__(256) void k_final(const float* __restrict__ x,
                                               const float* __restrict__ w,
                                               float* __restrict__ out) {
    const int b = blockIdx.x >> 7, kc = blockIdx.x & 127;  // grid 512
    const int d = threadIdx.x;
    const int k0 = kc * 32;
    float acc = 0.f;
    const float* xp = x + (size_t)(b * S_ + k0) * D_ + d;
    const float* wp = w + b * S_ + k0;
#pragma unroll 8
    for (int kk = 0; kk < 32; ++kk) acc += wp[kk] * xp[(size_t)kk * D_];
    atomicAdd(&out[b * D_ + d], acc);
}

extern "C" void kernel_launch(void* const* d_in, const int* in_sizes, int n_in,
                              void* d_out, int out_size, void* d_ws, size_t ws_size,
                              hipStream_t stream) {
    const float* x    = (const float*)d_in[0];   // [4,4096,256]
    const float* W    = (const float*)d_in[1];   // [512,256]
    const float* bias = (const float*)d_in[2];   // [512]
    float* out = (float*)d_out;                  // [4,256]

    char* ws = (char*)d_ws;
    u8*    Qi = (u8*)ws;                                  // 4 MiB
    u8*    Ki = Qi + (size_t)B_ * S_ * D_;                // 4 MiB
    float* Z  = (float*)(ws + 8388608);                   // 64 KiB
    float* w  = Z + B_ * S_;                              // 64 KiB
    u16*   Wb = (u16*)(w + B_ * S_);                      // 256 KiB

    k_convw<<<E_ * D_ / 256, 256, 0, stream>>>(W, Wb, Z, w, out);
    k_proj <<<512, 256, 0, stream>>>(x, Wb, bias, Qi, Ki);
    k_passA<<<512, 256, 0, stream>>>(Qi, Ki, Z);
    k_passB<<<512, 256, 0, stream>>>(Qi, Ki, Z, w);
    k_final<<<512, 256, 0, stream>>>(x, w, out);
}